// Round 6
// baseline (379.251 us; speedup 1.0000x reference)
//
#include <hip/hip_runtime.h>
#include <stdint.h>

typedef unsigned short u16;
typedef __attribute__((ext_vector_type(8))) short bf16x8;
typedef __attribute__((ext_vector_type(8))) unsigned short us8;
typedef __attribute__((ext_vector_type(4))) float f32x4;

typedef __attribute__((address_space(1))) void as1_void;
typedef __attribute__((address_space(3))) void as3_void;

#define S_LEN 2048
#define DMODEL 1024
#define DH 64
#define NHEADS 16
#define NB 4
#define GM (NB * S_LEN)   // 8192
#define GN DMODEL         // 1024
#define GK DMODEL         // 1024
#define SCALE 0.03125f    // 1/sqrt(1024)

__device__ __forceinline__ void gload16(const void* g, void* l) {
  __builtin_amdgcn_global_load_lds((const as1_void*)g, (as3_void*)l, 16, 0, 0);
}
__device__ __forceinline__ float bf2f(u16 u) {
  union { unsigned int i; float f; } x; x.i = ((unsigned int)u) << 16; return x.f;
}
__device__ __forceinline__ u16 f2bf(float f) {
  union { float f; unsigned int i; } x; x.f = f;
  unsigned int u = x.i + 0x7fffu + ((x.i >> 16) & 1u);
  return (u16)(u >> 16);
}
__device__ __forceinline__ f32x4 mfma16(bf16x8 a, bf16x8 b, f32x4 c) {
  return __builtin_amdgcn_mfma_f32_16x16x32_bf16(a, b, c, 0, 0, 0);
}
__device__ __forceinline__ void nt_store4(f32x4 v, float* p) {
  __builtin_nontemporal_store(v, (f32x4*)p);
}

// ---------------------------------------------------------------------------
// fp32 -> bf16 converts, batched
// ---------------------------------------------------------------------------
__device__ __forceinline__ void cvt_chunk(const float* s, u16* d, int i) {
  const f32x4 a = *(const f32x4*)(s + (size_t)i * 8);
  const f32x4 b = *(const f32x4*)(s + (size_t)i * 8 + 4);
  us8 o;
  o[0] = f2bf(a[0]); o[1] = f2bf(a[1]); o[2] = f2bf(a[2]); o[3] = f2bf(a[3]);
  o[4] = f2bf(b[0]); o[5] = f2bf(b[1]); o[6] = f2bf(b[2]); o[7] = f2bf(b[3]);
  *(us8*)(d + (size_t)i * 8) = o;
}
__global__ __launch_bounds__(256)
void cvt3(const float* __restrict__ s0, const float* __restrict__ s1,
          const float* __restrict__ s2, u16* __restrict__ d0,
          u16* __restrict__ d1, u16* __restrict__ d2, int n8) {
  const int i = blockIdx.x * 256 + threadIdx.x;
  if (i >= n8) return;
  const float* s; u16* d;
  if (blockIdx.y == 0)      { s = s0; d = d0; }
  else if (blockIdx.y == 1) { s = s1; d = d1; }
  else                      { s = s2; d = d2; }
  cvt_chunk(s, d, i);
}
__global__ __launch_bounds__(256)
void cvt4(const float* __restrict__ s0, const float* __restrict__ s1,
          const float* __restrict__ s2, const float* __restrict__ s3,
          u16* __restrict__ d0, u16* __restrict__ d1,
          u16* __restrict__ d2, u16* __restrict__ d3, int n8) {
  const int i = blockIdx.x * 256 + threadIdx.x;
  if (i >= n8) return;
  const float* s; u16* d;
  if (blockIdx.y == 0)      { s = s0; d = d0; }
  else if (blockIdx.y == 1) { s = s1; d = d1; }
  else if (blockIdx.y == 2) { s = s2; d = d2; }
  else                      { s = s3; d = d3; }
  cvt_chunk(s, d, i);
}

// ---------------------------------------------------------------------------
// GEMM body: C[8192,1024] = A[8192,1024] @ W[1024,1024]^T + bias
// 128x128 tile, BK=64, 4 waves (2x2), 64x64/wave, 2-phase LDS double-buffer.
// Epilogue bounces C tile through LDS for full-line global stores.
// ---------------------------------------------------------------------------
template<bool OUTF>
__device__ __forceinline__ void gemm_body(const u16* __restrict__ A,
                                          const u16* __restrict__ W,
                                          const float* __restrict__ bias,
                                          void* __restrict__ Cv,
                                          u16* smem) {
  u16* As = smem;
  u16* Bs = smem + 2 * 8192;
  const int tid  = threadIdx.x;
  const int lane = tid & 63;
  const int wv   = tid >> 6;
  const int wr   = wv >> 1, wc = wv & 1;
  const int rlow = lane & 15, rhi = lane >> 4;
  const int m0 = blockIdx.x * 128;
  const int n0 = blockIdx.y * 128;

  f32x4 acc[4][4];
#pragma unroll
  for (int i = 0; i < 4; ++i)
#pragma unroll
    for (int j = 0; j < 4; ++j) acc[i][j] = (f32x4){0.f, 0.f, 0.f, 0.f};

#define STAGE_G(bufi, kk)                                                     \
  {                                                                           \
    _Pragma("unroll")                                                         \
    for (int i = 0; i < 4; ++i) {                                             \
      const int c = i * 256 + tid;                                            \
      const int row = c >> 3, cw = c & 7;                                     \
      const int koff = ((kk) << 6) + ((cw ^ (row & 7)) << 3);                 \
      gload16(A + (size_t)(m0 + row) * GK + koff,                             \
              &As[(bufi) * 8192 + ((c - lane) << 3)]);                        \
      gload16(W + (size_t)(n0 + row) * GK + koff,                             \
              &Bs[(bufi) * 8192 + ((c - lane) << 3)]);                        \
    }                                                                         \
  }

  const int nk = GK >> 6;  // 16
  STAGE_G(0, 0);
  __syncthreads();
  int buf = 0;
  for (int kk = 0; kk < nk; ++kk) {
    if (kk + 1 < nk) STAGE_G(buf ^ 1, kk + 1);
    const u16* Ab = &As[buf * 8192];
    const u16* Bb = &Bs[buf * 8192];
    bf16x8 af[4][2], bfr[4][2];
#pragma unroll
    for (int mi = 0; mi < 4; ++mi) {
      const int row = wr * 64 + mi * 16 + rlow;
#pragma unroll
      for (int k2 = 0; k2 < 2; ++k2)
        af[mi][k2] = *(const bf16x8*)&Ab[row * 64 + (((rhi + k2 * 4) ^ (row & 7)) << 3)];
    }
#pragma unroll
    for (int ni = 0; ni < 4; ++ni) {
      const int row = wc * 64 + ni * 16 + rlow;
#pragma unroll
      for (int k2 = 0; k2 < 2; ++k2)
        bfr[ni][k2] = *(const bf16x8*)&Bb[row * 64 + (((rhi + k2 * 4) ^ (row & 7)) << 3)];
    }
#pragma unroll
    for (int mi = 0; mi < 4; ++mi)
#pragma unroll
      for (int ni = 0; ni < 4; ++ni) {
        acc[mi][ni] = mfma16(af[mi][0], bfr[ni][0], acc[mi][ni]);
        acc[mi][ni] = mfma16(af[mi][1], bfr[ni][1], acc[mi][ni]);
      }
    __syncthreads();  // drains vmcnt: next tile resident; buf safe to reuse
    buf ^= 1;
  }
#undef STAGE_G

  // ---- epilogue: bounce C tile through LDS for full-line stores
  if constexpr (OUTF) {
    float* Cs = (float*)smem;               // [128][128] fp32 = 64 KB
#pragma unroll
    for (int ni = 0; ni < 4; ++ni) {
      const int col = wc * 64 + ni * 16 + rlow;
      const float bv = bias[n0 + col];
#pragma unroll
      for (int mi = 0; mi < 4; ++mi)
#pragma unroll
        for (int r = 0; r < 4; ++r)
          Cs[(wr * 64 + mi * 16 + rhi * 4 + r) * 128 + col] = acc[mi][ni][r] + bv;
    }
    __syncthreads();
#pragma unroll
    for (int i = 0; i < 16; ++i) {
      const int c = i * 256 + tid;          // 4096 f32x4 chunks
      const int row = c >> 5, cw = c & 31;
      const f32x4 t = *(const f32x4*)&Cs[row * 128 + cw * 4];
      nt_store4(t, &((float*)Cv)[(size_t)(m0 + row) * GN + n0 + cw * 4]);
    }
  } else {
    u16* Cs = smem;                          // [128][144] bf16 (padded)
#pragma unroll
    for (int ni = 0; ni < 4; ++ni) {
      const int col = wc * 64 + ni * 16 + rlow;
      const float bv = bias[n0 + col];
#pragma unroll
      for (int mi = 0; mi < 4; ++mi)
#pragma unroll
        for (int r = 0; r < 4; ++r)
          Cs[(wr * 64 + mi * 16 + rhi * 4 + r) * 144 + col] = f2bf(acc[mi][ni][r] + bv);
    }
    __syncthreads();
#pragma unroll
    for (int i = 0; i < 8; ++i) {
      const int c = i * 256 + tid;          // 2048 us8 chunks
      const int row = c >> 4, cw = c & 15;
      const us8 t = *(const us8*)&Cs[row * 144 + cw * 8];
      *(us8*)&((u16*)Cv)[(size_t)(m0 + row) * GN + n0 + cw * 8] = t;
    }
  }
}

__global__ __launch_bounds__(256, 2)
void gemm_qkv(const u16* __restrict__ xq, const u16* __restrict__ xk,
              const u16* __restrict__ xv, const u16* __restrict__ wq,
              const u16* __restrict__ wk, const u16* __restrict__ wv,
              const float* __restrict__ bq, const float* __restrict__ bk,
              const float* __restrict__ bv, u16* __restrict__ oq,
              u16* __restrict__ ok, u16* __restrict__ ov) {
  __shared__ u16 smem[4 * 8192];
  const u16 *A, *W; const float* bias; u16* C;
  if (blockIdx.z == 0)      { A = xq; W = wq; bias = bq; C = oq; }
  else if (blockIdx.z == 1) { A = xk; W = wk; bias = bk; C = ok; }
  else                      { A = xv; W = wv; bias = bv; C = ov; }
  gemm_body<false>(A, W, bias, C, smem);
}

__global__ __launch_bounds__(256, 2)
void gemm_o(const u16* __restrict__ A, const u16* __restrict__ W,
            const float* __restrict__ bias, float* __restrict__ C) {
  __shared__ u16 smem[4 * 8192];
  gemm_body<true>(A, W, bias, C, smem);
}

// ---------------------------------------------------------------------------
// Fused causal attention. Block bid handles TWO q-tiles {15-pr, pr}
// (pr = bid>>6) for one (b,h) -> 512 blocks x uniform 17 tile-units.
// Pass 1: QK^T -> per-row sum of exp. Pass 2: recompute QK^T, bf16 weights
// into own-wave Ws rows, per-wave full-line NT fp32 stores (no cross-wave
// barrier needed: PV A-frag and stores read own-wave rows only), PV MFMA.
// LDS: Qs/Ws union -> 67 KB -> 2 blocks/CU at (512,4).
// ---------------------------------------------------------------------------
__global__ __launch_bounds__(512, 4)
void attn_fused(const u16* __restrict__ qh, const u16* __restrict__ kh,
                const u16* __restrict__ vh, float* __restrict__ wout,
                u16* __restrict__ am)
{
  __shared__ u16 smem[34304];          // 67 KB
  u16* Ws = smem;                      // [128][136]
  u16* Qs = smem;                      // [128][64]  (prologue only, union)
  u16* Ks = smem + 17408;              // [128][64]
  u16* VT = smem + 17408 + 8192;       // [64][136]

  const int tid = threadIdx.x, lane = tid & 63, wv = tid >> 6;
  const int rlow = lane & 15, rhi = lane >> 4;
  const int bid = blockIdx.x;
  const int bh  = bid & 63;            // consecutive blocks spread across heads
  const int pr  = bid >> 6;            // 0..7: q-tile pair {15-pr, pr}
  const int b = bh >> 4, h = bh & 15;
  const size_t headoff = (size_t)b * S_LEN * DMODEL + h * DH;

  for (int sel = 0; sel < 2; ++sel) {
    const int qt = sel ? pr : 15 - pr;   // heavy tile first
    const int q0 = qt << 7;
    __syncthreads();                     // smem reusable (prev sel done)

    // ---- stage Q tile (swizzled source -> linear LDS)
#pragma unroll
    for (int i = 0; i < 2; ++i) {
      const int c = i * 512 + tid;
      const int row = c >> 3, cw = c & 7;
      gload16(qh + headoff + (size_t)(q0 + row) * DMODEL + ((cw ^ (row & 7)) << 3),
              &Qs[(c - lane) << 3]);
    }
    __syncthreads();
    bf16x8 qf[2];
    {
      const int row = wv * 16 + rlow;
#pragma unroll
      for (int k2 = 0; k2 < 2; ++k2)
        qf[k2] = *(const bf16x8*)&Qs[row * 64 + (((rhi + k2 * 4) ^ (row & 7)) << 3)];
    }

    const int gi_base = q0 + wv * 16 + rhi * 4;
    float ssum[4] = {0.f, 0.f, 0.f, 0.f};

    // ---------------- pass 1: row sums of exp ----------------
    for (int jt = 0; jt <= qt; ++jt) {
      __syncthreads();
#pragma unroll
      for (int i = 0; i < 2; ++i) {
        const int c = i * 512 + tid;
        const int row = c >> 3, cw = c & 7;
        gload16(kh + headoff + (size_t)(jt * 128 + row) * DMODEL + ((cw ^ (row & 7)) << 3),
                &Ks[(c - lane) << 3]);
      }
      __syncthreads();
      const bool diag = (jt == qt);
      float pexp[4] = {0.f, 0.f, 0.f, 0.f};
#pragma unroll
      for (int half = 0; half < 2; ++half) {
        f32x4 acc[4];
#pragma unroll
        for (int ni = 0; ni < 4; ++ni) acc[ni] = (f32x4){0.f, 0.f, 0.f, 0.f};
#pragma unroll
        for (int k2 = 0; k2 < 2; ++k2) {
#pragma unroll
          for (int ni = 0; ni < 4; ++ni) {
            const int row = (half * 4 + ni) * 16 + rlow;
            bf16x8 kf = *(const bf16x8*)&Ks[row * 64 + (((rhi + k2 * 4) ^ (row & 7)) << 3)];
            acc[ni] = mfma16(qf[k2], kf, acc[ni]);
          }
        }
#pragma unroll
        for (int ni = 0; ni < 4; ++ni) {
          const int gj = jt * 128 + (half * 4 + ni) * 16 + rlow;
#pragma unroll
          for (int r = 0; r < 4; ++r) {
            if (!diag || gj <= gi_base + r) pexp[r] += __expf(acc[ni][r] * SCALE);
          }
        }
      }
#pragma unroll
      for (int r = 0; r < 4; ++r) {
        float p = pexp[r];
        p += __shfl_xor(p, 1);
        p += __shfl_xor(p, 2);
        p += __shfl_xor(p, 4);
        p += __shfl_xor(p, 8);
        ssum[r] += p;
      }
    }
    float inv_s[4];
#pragma unroll
    for (int r = 0; r < 4; ++r) inv_s[r] = 1.f / ssum[r];

    f32x4 opv[4];
#pragma unroll
    for (int ni = 0; ni < 4; ++ni) opv[ni] = (f32x4){0.f, 0.f, 0.f, 0.f};

    // ---------------- pass 2: weights + PV ----------------
    for (int jt = 0; jt <= qt; ++jt) {
      __syncthreads();   // prev iter's readers of Ks/VT complete
#pragma unroll
      for (int i = 0; i < 2; ++i) {
        const int c = i * 512 + tid;
        const int row = c >> 3, cw = c & 7;
        gload16(kh + headoff + (size_t)(jt * 128 + row) * DMODEL + ((cw ^ (row & 7)) << 3),
                &Ks[(c - lane) << 3]);
      }
      // stage V transposed: VT[d][j]
#pragma unroll
      for (int i = 0; i < 2; ++i) {
        const int c = i * 512 + tid;
        const int j = c >> 3, d0 = (c & 7) << 3;
        bf16x8 vv = *(const bf16x8*)(vh + headoff + (size_t)(jt * 128 + j) * DMODEL + d0);
#pragma unroll
        for (int e = 0; e < 8; ++e) VT[(d0 + e) * 136 + j] = (u16)vv[e];
      }
      __syncthreads();
      const bool diag = (jt == qt);
#pragma unroll
      for (int half = 0; half < 2; ++half) {
        f32x4 acc[4];
#pragma unroll
        for (int ni = 0; ni < 4; ++ni) acc[ni] = (f32x4){0.f, 0.f, 0.f, 0.f};
#pragma unroll
        for (int k2 = 0; k2 < 2; ++k2) {
#pragma unroll
          for (int ni = 0; ni < 4; ++ni) {
            const int row = (half * 4 + ni) * 16 + rlow;
            bf16x8 kf = *(const bf16x8*)&Ks[row * 64 + (((rhi + k2 * 4) ^ (row & 7)) << 3)];
            acc[ni] = mfma16(qf[k2], kf, acc[ni]);
          }
        }
#pragma unroll
        for (int ni = 0; ni < 4; ++ni) {
          const int col = (half * 4 + ni) * 16 + rlow;
          const int gj = jt * 128 + col;
#pragma unroll
          for (int r = 0; r < 4; ++r) {
            float w = 0.f;
            if (!diag || gj <= gi_base + r) w = __expf(acc[ni][r] * SCALE) * inv_s[r];
            Ws[(wv * 16 + rhi * 4 + r) * 136 + col] = f2bf(w);
          }
        }
      }
      // NO cross-wave barrier: stores + PV A-frag read own-wave Ws rows only
      // (intra-wave LDS ordering via lgkmcnt).
      {
        const size_t wbase = ((size_t)bh * S_LEN + q0) * S_LEN + (size_t)jt * 128;
        const int hrow = lane >> 5;       // half-wave row select
        const int cw = lane & 31;
#pragma unroll
        for (int it = 0; it < 8; ++it) {
          const int row = wv * 16 + it * 2 + hrow;
          f32x4 t;
          t[0] = bf2f(Ws[row * 136 + cw * 4 + 0]);
          t[1] = bf2f(Ws[row * 136 + cw * 4 + 1]);
          t[2] = bf2f(Ws[row * 136 + cw * 4 + 2]);
          t[3] = bf2f(Ws[row * 136 + cw * 4 + 3]);
          nt_store4(t, wout + wbase + (size_t)row * S_LEN + cw * 4);
        }
      }
      // PV: A from Ws (this wave's 16 rows), B from VT
#pragma unroll
      for (int k4 = 0; k4 < 4; ++k4) {
        const bf16x8 afr = *(const bf16x8*)&Ws[(wv * 16 + rlow) * 136 + rhi * 8 + k4 * 32];
#pragma unroll
        for (int ni = 0; ni < 4; ++ni) {
          const bf16x8 vfr = *(const bf16x8*)&VT[(ni * 16 + rlow) * 136 + rhi * 8 + k4 * 32];
          opv[ni] = mfma16(afr, vfr, opv[ni]);
        }
      }
    }

    // ---- zero tiles above the diagonal (every byte written exactly once)
    {
      const f32x4 z = {0.f, 0.f, 0.f, 0.f};
      for (int jt = qt + 1; jt < 16; ++jt) {
        const size_t wbase = ((size_t)bh * S_LEN + q0) * S_LEN + (size_t)jt * 128;
#pragma unroll
        for (int i = 0; i < 8; ++i) {
          const int c = i * 512 + tid;
          const int row = c >> 5, cw = c & 31;
          nt_store4(z, wout + wbase + (size_t)row * S_LEN + cw * 4);
        }
      }
    }

    // ---- merged attention output, bounced through LDS for full-line stores
    __syncthreads();                     // all PV reads of Ws done
    {
      u16* Os = smem;                    // [128][72]
#pragma unroll
      for (int ni = 0; ni < 4; ++ni)
#pragma unroll
        for (int r = 0; r < 4; ++r)
          Os[(wv * 16 + rhi * 4 + r) * 72 + ni * 16 + rlow] = f2bf(opv[ni][r]);
      __syncthreads();
#pragma unroll
      for (int i = 0; i < 2; ++i) {
        const int c = i * 512 + tid;     // 1024 us8 chunks: 128 rows x 8
        const int row = c >> 3, cw = c & 7;
        const us8 t = *(const us8*)&Os[row * 72 + cw * 8];
        *(us8*)(am + headoff + (size_t)(q0 + row) * DMODEL + cw * 8) = t;
      }
    }
  }
}

// ---------------------------------------------------------------------------
extern "C" void kernel_launch(void* const* d_in, const int* in_sizes, int n_in,
                              void* d_out, int out_size, void* d_ws, size_t ws_size,
                              hipStream_t stream) {
  const float* q  = (const float*)d_in[0];
  const float* k  = (const float*)d_in[1];
  const float* v  = (const float*)d_in[2];
  // d_in[3] = causal mask (int32) -- fixed triu(1), applied analytically
  const float* Wq = (const float*)d_in[4];
  const float* bq = (const float*)d_in[5];
  const float* Wk = (const float*)d_in[6];
  const float* bk = (const float*)d_in[7];
  const float* Wv = (const float*)d_in[8];
  const float* bv = (const float*)d_in[9];
  const float* Wo = (const float*)d_in[10];
  const float* bo = (const float*)d_in[11];

  const size_t proj_elems = (size_t)NB * S_LEN * DMODEL;  // 8388608
  const size_t w_elems    = (size_t)DMODEL * DMODEL;      // 1048576
  float* out0 = (float*)d_out;
  float* wts  = out0 + proj_elems;     // fp32 weights region (268.4M floats)

  // persistent bf16 scratch in d_ws (must survive attention kernel)
  u16* qh  = (u16*)d_ws;
  u16* kh  = qh + proj_elems;
  u16* vh  = kh + proj_elems;
  u16* am  = vh + proj_elems;
  u16* wco = am + proj_elems;          // bf16 Wo

  // transient bf16 scratch inside the (not-yet-written) weights region
  u16* xq = (u16*)wts;
  u16* xk = xq + proj_elems;
  u16* xv = xk + proj_elems;
  u16* wq_ = xv + proj_elems;
  u16* wk_ = wq_ + w_elems;
  u16* wv_ = wk_ + w_elems;

  const int n8x = (int)(proj_elems / 8);   // 1048576
  const int n8w = (int)(w_elems / 8);      // 131072

  cvt3<<<dim3(n8x / 256, 3), dim3(256), 0, stream>>>(q, k, v, xq, xk, xv, n8x);
  cvt4<<<dim3(n8w / 256, 4), dim3(256), 0, stream>>>(Wq, Wk, Wv, Wo,
                                                     wq_, wk_, wv_, wco, n8w);
  gemm_qkv<<<dim3(64, 8, 3), dim3(256), 0, stream>>>(xq, xk, xv, wq_, wk_, wv_,
                                                     bq, bk, bv, qh, kh, vh);
  attn_fused<<<dim3(512), dim3(512), 0, stream>>>(qh, kh, vh, wts, am);
  gemm_o<<<dim3(64, 8), dim3(256), 0, stream>>>(am, wco, bo, out0);
}

// Round 7
// 369.784 us; speedup vs baseline: 1.0256x; 1.0256x over previous
//
#include <hip/hip_runtime.h>
#include <stdint.h>

typedef unsigned short u16;
typedef __attribute__((ext_vector_type(8))) short bf16x8;
typedef __attribute__((ext_vector_type(8))) unsigned short us8;
typedef __attribute__((ext_vector_type(4))) float f32x4;

typedef __attribute__((address_space(1))) void as1_void;
typedef __attribute__((address_space(3))) void as3_void;

#define S_LEN 2048
#define DMODEL 1024
#define DH 64
#define NHEADS 16
#define NB 4
#define GM (NB * S_LEN)   // 8192
#define GN DMODEL         // 1024
#define GK DMODEL         // 1024
#define SCALE 0.03125f    // 1/sqrt(1024)

__device__ __forceinline__ void gload16(const void* g, void* l) {
  __builtin_amdgcn_global_load_lds((const as1_void*)g, (as3_void*)l, 16, 0, 0);
}
__device__ __forceinline__ float bf2f(u16 u) {
  union { unsigned int i; float f; } x; x.i = ((unsigned int)u) << 16; return x.f;
}
__device__ __forceinline__ u16 f2bf(float f) {
  union { float f; unsigned int i; } x; x.f = f;
  unsigned int u = x.i + 0x7fffu + ((x.i >> 16) & 1u);
  return (u16)(u >> 16);
}
__device__ __forceinline__ f32x4 mfma16(bf16x8 a, bf16x8 b, f32x4 c) {
  return __builtin_amdgcn_mfma_f32_16x16x32_bf16(a, b, c, 0, 0, 0);
}
__device__ __forceinline__ void nt_store4(f32x4 v, float* p) {
  __builtin_nontemporal_store(v, (f32x4*)p);
}
__device__ __forceinline__ us8 cvt8(f32x4 a, f32x4 b) {
  us8 o;
  o[0] = f2bf(a[0]); o[1] = f2bf(a[1]); o[2] = f2bf(a[2]); o[3] = f2bf(a[3]);
  o[4] = f2bf(b[0]); o[5] = f2bf(b[1]); o[6] = f2bf(b[2]); o[7] = f2bf(b[3]);
  return o;
}

// ---------------------------------------------------------------------------
// fp32 -> bf16 convert for the 4 weight matrices (small, 8 MB total)
// ---------------------------------------------------------------------------
__global__ __launch_bounds__(256)
void cvt4(const float* __restrict__ s0, const float* __restrict__ s1,
          const float* __restrict__ s2, const float* __restrict__ s3,
          u16* __restrict__ d0, u16* __restrict__ d1,
          u16* __restrict__ d2, u16* __restrict__ d3, int n8) {
  const int i = blockIdx.x * 256 + threadIdx.x;
  if (i >= n8) return;
  const float* s; u16* d;
  if (blockIdx.y == 0)      { s = s0; d = d0; }
  else if (blockIdx.y == 1) { s = s1; d = d1; }
  else if (blockIdx.y == 2) { s = s2; d = d2; }
  else                      { s = s3; d = d3; }
  const f32x4 a = *(const f32x4*)(s + (size_t)i * 8);
  const f32x4 b = *(const f32x4*)(s + (size_t)i * 8 + 4);
  *(us8*)(d + (size_t)i * 8) = cvt8(a, b);
}

// ---------------------------------------------------------------------------
// GEMM body: C[8192,1024] = A[8192,1024] @ W[1024,1024]^T + bias
// 128x128 tile, BK=64, 4 waves (2x2), 64x64/wave, 2-phase LDS double-buffer.
// AF32: A is raw fp32; reg-staged (T14 issue-early/write-late) + converted to
// bf16 during staging. Else A is bf16 via global_load_lds.
// Epilogue bounces C tile through LDS for full-line global stores.
// ---------------------------------------------------------------------------
template<bool AF32, bool OUTF>
__device__ __forceinline__ void gemm_body(const void* __restrict__ Av,
                                          const u16* __restrict__ W,
                                          const float* __restrict__ bias,
                                          void* __restrict__ Cv,
                                          u16* smem) {
  u16* As = smem;
  u16* Bs = smem + 2 * 8192;
  const int tid  = threadIdx.x;
  const int lane = tid & 63;
  const int wv   = tid >> 6;
  const int wr   = wv >> 1, wc = wv & 1;
  const int rlow = lane & 15, rhi = lane >> 4;
  const int m0 = blockIdx.x * 128;
  const int n0 = blockIdx.y * 128;

  const u16*   Ab16 = (const u16*)Av;
  const float* Af32 = (const float*)Av;

  f32x4 acc[4][4];
#pragma unroll
  for (int i = 0; i < 4; ++i)
#pragma unroll
    for (int j = 0; j < 4; ++j) acc[i][j] = (f32x4){0.f, 0.f, 0.f, 0.f};

#define STAGE_B16(bufi, kk)                                                   \
  {                                                                           \
    _Pragma("unroll")                                                         \
    for (int i = 0; i < 4; ++i) {                                             \
      const int c = i * 256 + tid;                                            \
      const int row = c >> 3, cw = c & 7;                                     \
      const int koff = ((kk) << 6) + ((cw ^ (row & 7)) << 3);                 \
      gload16(W + (size_t)(n0 + row) * GK + koff,                             \
              &Bs[(bufi) * 8192 + ((c - lane) << 3)]);                        \
    }                                                                         \
  }
#define STAGE_A16(bufi, kk)                                                   \
  {                                                                           \
    _Pragma("unroll")                                                         \
    for (int i = 0; i < 4; ++i) {                                             \
      const int c = i * 256 + tid;                                            \
      const int row = c >> 3, cw = c & 7;                                     \
      const int koff = ((kk) << 6) + ((cw ^ (row & 7)) << 3);                 \
      gload16(Ab16 + (size_t)(m0 + row) * GK + koff,                          \
              &As[(bufi) * 8192 + ((c - lane) << 3)]);                        \
    }                                                                         \
  }
#define LOAD_AF32(kk)                                                         \
  {                                                                           \
    _Pragma("unroll")                                                         \
    for (int i = 0; i < 4; ++i) {                                             \
      const int c = i * 256 + tid;                                            \
      const int row = c >> 3, cw = c & 7;                                     \
      const float* src = Af32 + (size_t)(m0 + row) * GK + ((kk) << 6) +       \
                         ((cw ^ (row & 7)) << 3);                             \
      areg0[i] = *(const f32x4*)src;                                          \
      areg1[i] = *(const f32x4*)(src + 4);                                    \
    }                                                                         \
  }
#define WRITE_AF32(bufi)                                                      \
  {                                                                           \
    _Pragma("unroll")                                                         \
    for (int i = 0; i < 4; ++i) {                                             \
      const int c = i * 256 + tid;                                            \
      *(us8*)&As[(bufi) * 8192 + (c << 3)] = cvt8(areg0[i], areg1[i]);        \
    }                                                                         \
  }

  f32x4 areg0[4], areg1[4];
  const int nk = GK >> 6;  // 16

  if constexpr (AF32) {
    LOAD_AF32(0);
    STAGE_B16(0, 0);
    WRITE_AF32(0);
  } else {
    STAGE_A16(0, 0);
    STAGE_B16(0, 0);
  }
  __syncthreads();
  int buf = 0;
  for (int kk = 0; kk < nk; ++kk) {
    if (kk + 1 < nk) {
      if constexpr (AF32) {
        LOAD_AF32(kk + 1);          // issue loads; convert AFTER MFMA below
        STAGE_B16(buf ^ 1, kk + 1);
      } else {
        STAGE_A16(buf ^ 1, kk + 1);
        STAGE_B16(buf ^ 1, kk + 1);
      }
    }
    const u16* Ab = &As[buf * 8192];
    const u16* Bb = &Bs[buf * 8192];
    bf16x8 af[4][2], bfr[4][2];
#pragma unroll
    for (int mi = 0; mi < 4; ++mi) {
      const int row = wr * 64 + mi * 16 + rlow;
#pragma unroll
      for (int k2 = 0; k2 < 2; ++k2)
        af[mi][k2] = *(const bf16x8*)&Ab[row * 64 + (((rhi + k2 * 4) ^ (row & 7)) << 3)];
    }
#pragma unroll
    for (int ni = 0; ni < 4; ++ni) {
      const int row = wc * 64 + ni * 16 + rlow;
#pragma unroll
      for (int k2 = 0; k2 < 2; ++k2)
        bfr[ni][k2] = *(const bf16x8*)&Bb[row * 64 + (((rhi + k2 * 4) ^ (row & 7)) << 3)];
    }
#pragma unroll
    for (int mi = 0; mi < 4; ++mi)
#pragma unroll
      for (int ni = 0; ni < 4; ++ni) {
        acc[mi][ni] = mfma16(af[mi][0], bfr[ni][0], acc[mi][ni]);
        acc[mi][ni] = mfma16(af[mi][1], bfr[ni][1], acc[mi][ni]);
      }
    if constexpr (AF32) {
      if (kk + 1 < nk) WRITE_AF32(buf ^ 1);   // T14 write-late
    }
    __syncthreads();  // drains vmcnt+lgkmcnt: next tile resident
    buf ^= 1;
  }
#undef STAGE_B16
#undef STAGE_A16
#undef LOAD_AF32
#undef WRITE_AF32

  // ---- epilogue: bounce C tile through LDS for full-line stores
  if constexpr (OUTF) {
    float* Cs = (float*)smem;               // [128][128] fp32 = 64 KB
#pragma unroll
    for (int ni = 0; ni < 4; ++ni) {
      const int col = wc * 64 + ni * 16 + rlow;
      const float bv = bias[n0 + col];
#pragma unroll
      for (int mi = 0; mi < 4; ++mi)
#pragma unroll
        for (int r = 0; r < 4; ++r)
          Cs[(wr * 64 + mi * 16 + rhi * 4 + r) * 128 + col] = acc[mi][ni][r] + bv;
    }
    __syncthreads();
#pragma unroll
    for (int i = 0; i < 16; ++i) {
      const int c = i * 256 + tid;          // 4096 f32x4 chunks
      const int row = c >> 5, cw = c & 31;
      const f32x4 t = *(const f32x4*)&Cs[row * 128 + cw * 4];
      nt_store4(t, &((float*)Cv)[(size_t)(m0 + row) * GN + n0 + cw * 4]);
    }
  } else {
    u16* Cs = smem;                          // [128][144] bf16 (padded)
#pragma unroll
    for (int ni = 0; ni < 4; ++ni) {
      const int col = wc * 64 + ni * 16 + rlow;
      const float bv = bias[n0 + col];
#pragma unroll
      for (int mi = 0; mi < 4; ++mi)
#pragma unroll
        for (int r = 0; r < 4; ++r)
          Cs[(wr * 64 + mi * 16 + rhi * 4 + r) * 144 + col] = f2bf(acc[mi][ni][r] + bv);
    }
    __syncthreads();
#pragma unroll
    for (int i = 0; i < 8; ++i) {
      const int c = i * 256 + tid;          // 2048 us8 chunks
      const int row = c >> 4, cw = c & 15;
      const us8 t = *(const us8*)&Cs[row * 144 + cw * 8];
      *(us8*)&((u16*)Cv)[(size_t)(m0 + row) * GN + n0 + cw * 8] = t;
    }
  }
}

__global__ __launch_bounds__(256, 2)
void gemm_qkv(const float* __restrict__ xq, const float* __restrict__ xk,
              const float* __restrict__ xv, const u16* __restrict__ wq,
              const u16* __restrict__ wk, const u16* __restrict__ wv,
              const float* __restrict__ bq, const float* __restrict__ bk,
              const float* __restrict__ bv, u16* __restrict__ oq,
              u16* __restrict__ ok, u16* __restrict__ ov) {
  __shared__ u16 smem[4 * 8192];
  const float* A; const u16* W; const float* bias; u16* C;
  if (blockIdx.z == 0)      { A = xq; W = wq; bias = bq; C = oq; }
  else if (blockIdx.z == 1) { A = xk; W = wk; bias = bk; C = ok; }
  else                      { A = xv; W = wv; bias = bv; C = ov; }
  gemm_body<true, false>(A, W, bias, C, smem);
}

__global__ __launch_bounds__(256, 2)
void gemm_o(const u16* __restrict__ A, const u16* __restrict__ W,
            const float* __restrict__ bias, float* __restrict__ C) {
  __shared__ u16 smem[4 * 8192];
  gemm_body<false, true>(A, W, bias, C, smem);
}

// ---------------------------------------------------------------------------
// Fused causal attention for one (b,h, 128-row Q tile).  [r5 version]
// Pass 1: QK^T -> per-row sum of exp. Pass 2: recompute QK^T, bf16 weights
// into Ws, barrier, full-line NT f32x4 store of the weight tile, PV MFMA.
// LDS: Qs/Ws union -> 67 KB -> 2 blocks/CU at (512,4).
// ---------------------------------------------------------------------------
__global__ __launch_bounds__(512, 4)
void attn_fused(const u16* __restrict__ qh, const u16* __restrict__ kh,
                const u16* __restrict__ vh, float* __restrict__ wout,
                u16* __restrict__ am)
{
  __shared__ u16 smem[34304];          // 67 KB
  u16* Ws = smem;                      // [128][136]
  u16* Qs = smem;                      // [128][64]  (prologue only, union)
  u16* Ks = smem + 17408;              // [128][64]
  u16* VT = smem + 17408 + 8192;       // [64][136]

  const int tid = threadIdx.x, lane = tid & 63, wv = tid >> 6;
  const int rlow = lane & 15, rhi = lane >> 4;
  const int idx = blockIdx.x;
  const int bh  = idx & 63;            // consecutive blocks spread across heads
  const int qt  = 15 - (idx >> 6);     // heaviest Q-tiles scheduled first
  const int b = bh >> 4, h = bh & 15;
  const int q0 = qt << 7;
  const size_t headoff = (size_t)b * S_LEN * DMODEL + h * DH;

  // ---- stage Q tile (swizzled source -> linear LDS)
#pragma unroll
  for (int i = 0; i < 2; ++i) {
    const int c = i * 512 + tid;
    const int row = c >> 3, cw = c & 7;
    gload16(qh + headoff + (size_t)(q0 + row) * DMODEL + ((cw ^ (row & 7)) << 3),
            &Qs[(c - lane) << 3]);
  }
  __syncthreads();
  bf16x8 qf[2];
  {
    const int row = wv * 16 + rlow;
#pragma unroll
    for (int k2 = 0; k2 < 2; ++k2)
      qf[k2] = *(const bf16x8*)&Qs[row * 64 + (((rhi + k2 * 4) ^ (row & 7)) << 3)];
  }

  const int gi_base = q0 + wv * 16 + rhi * 4;
  float ssum[4] = {0.f, 0.f, 0.f, 0.f};

  // ---------------- pass 1: row sums of exp ----------------
  for (int jt = 0; jt <= qt; ++jt) {
    __syncthreads();
#pragma unroll
    for (int i = 0; i < 2; ++i) {
      const int c = i * 512 + tid;
      const int row = c >> 3, cw = c & 7;
      gload16(kh + headoff + (size_t)(jt * 128 + row) * DMODEL + ((cw ^ (row & 7)) << 3),
              &Ks[(c - lane) << 3]);
    }
    __syncthreads();
    const bool diag = (jt == qt);
    float pexp[4] = {0.f, 0.f, 0.f, 0.f};
#pragma unroll
    for (int half = 0; half < 2; ++half) {
      f32x4 acc[4];
#pragma unroll
      for (int ni = 0; ni < 4; ++ni) acc[ni] = (f32x4){0.f, 0.f, 0.f, 0.f};
#pragma unroll
      for (int k2 = 0; k2 < 2; ++k2) {
#pragma unroll
        for (int ni = 0; ni < 4; ++ni) {
          const int row = (half * 4 + ni) * 16 + rlow;
          bf16x8 kf = *(const bf16x8*)&Ks[row * 64 + (((rhi + k2 * 4) ^ (row & 7)) << 3)];
          acc[ni] = mfma16(qf[k2], kf, acc[ni]);
        }
      }
#pragma unroll
      for (int ni = 0; ni < 4; ++ni) {
        const int gj = jt * 128 + (half * 4 + ni) * 16 + rlow;
#pragma unroll
        for (int r = 0; r < 4; ++r) {
          if (!diag || gj <= gi_base + r) pexp[r] += __expf(acc[ni][r] * SCALE);
        }
      }
    }
#pragma unroll
    for (int r = 0; r < 4; ++r) {
      float p = pexp[r];
      p += __shfl_xor(p, 1);
      p += __shfl_xor(p, 2);
      p += __shfl_xor(p, 4);
      p += __shfl_xor(p, 8);
      ssum[r] += p;
    }
  }
  float inv_s[4];
#pragma unroll
  for (int r = 0; r < 4; ++r) inv_s[r] = 1.f / ssum[r];

  f32x4 opv[4];
#pragma unroll
  for (int ni = 0; ni < 4; ++ni) opv[ni] = (f32x4){0.f, 0.f, 0.f, 0.f};

  // ---------------- pass 2: weights + PV ----------------
  for (int jt = 0; jt <= qt; ++jt) {
    __syncthreads();   // prev iter's PV (VT/Ws readers) complete
#pragma unroll
    for (int i = 0; i < 2; ++i) {
      const int c = i * 512 + tid;
      const int row = c >> 3, cw = c & 7;
      gload16(kh + headoff + (size_t)(jt * 128 + row) * DMODEL + ((cw ^ (row & 7)) << 3),
              &Ks[(c - lane) << 3]);
    }
    // stage V transposed: VT[d][j]
#pragma unroll
    for (int i = 0; i < 2; ++i) {
      const int c = i * 512 + tid;
      const int j = c >> 3, d0 = (c & 7) << 3;
      bf16x8 vv = *(const bf16x8*)(vh + headoff + (size_t)(jt * 128 + j) * DMODEL + d0);
#pragma unroll
      for (int e = 0; e < 8; ++e) VT[(d0 + e) * 136 + j] = (u16)vv[e];
    }
    __syncthreads();
    const bool diag = (jt == qt);
#pragma unroll
    for (int half = 0; half < 2; ++half) {
      f32x4 acc[4];
#pragma unroll
      for (int ni = 0; ni < 4; ++ni) acc[ni] = (f32x4){0.f, 0.f, 0.f, 0.f};
#pragma unroll
      for (int k2 = 0; k2 < 2; ++k2) {
#pragma unroll
        for (int ni = 0; ni < 4; ++ni) {
          const int row = (half * 4 + ni) * 16 + rlow;
          bf16x8 kf = *(const bf16x8*)&Ks[row * 64 + (((rhi + k2 * 4) ^ (row & 7)) << 3)];
          acc[ni] = mfma16(qf[k2], kf, acc[ni]);
        }
      }
#pragma unroll
      for (int ni = 0; ni < 4; ++ni) {
        const int col = (half * 4 + ni) * 16 + rlow;
        const int gj = jt * 128 + col;
#pragma unroll
        for (int r = 0; r < 4; ++r) {
          float w = 0.f;
          if (!diag || gj <= gi_base + r) w = __expf(acc[ni][r] * SCALE) * inv_s[r];
          Ws[(wv * 16 + rhi * 4 + r) * 136 + col] = f2bf(w);
        }
      }
    }
    __syncthreads();   // Ws tile complete
    // full-line NONTEMPORAL fp32 store of the weights tile
    {
      const size_t wbase = ((size_t)bh * S_LEN + q0) * S_LEN + (size_t)jt * 128;
#pragma unroll
      for (int i = 0; i < 8; ++i) {
        const int c = i * 512 + tid;        // 4096 f32x4 chunks: 128 rows x 32
        const int row = c >> 5, cw = c & 31;
        f32x4 t;
        t[0] = bf2f(Ws[row * 136 + cw * 4 + 0]);
        t[1] = bf2f(Ws[row * 136 + cw * 4 + 1]);
        t[2] = bf2f(Ws[row * 136 + cw * 4 + 2]);
        t[3] = bf2f(Ws[row * 136 + cw * 4 + 3]);
        nt_store4(t, wout + wbase + (size_t)row * S_LEN + cw * 4);
      }
    }
    // PV: A from Ws (this wave's 16 rows), B from VT
#pragma unroll
    for (int k4 = 0; k4 < 4; ++k4) {
      const bf16x8 afr = *(const bf16x8*)&Ws[(wv * 16 + rlow) * 136 + rhi * 8 + k4 * 32];
#pragma unroll
      for (int ni = 0; ni < 4; ++ni) {
        const bf16x8 vfr = *(const bf16x8*)&VT[(ni * 16 + rlow) * 136 + rhi * 8 + k4 * 32];
        opv[ni] = mfma16(afr, vfr, opv[ni]);
      }
    }
  }

  // ---- zero tiles above the diagonal (every d_out byte written exactly once)
  {
    const f32x4 z = {0.f, 0.f, 0.f, 0.f};
    for (int jt = qt + 1; jt < 16; ++jt) {
      const size_t wbase = ((size_t)bh * S_LEN + q0) * S_LEN + (size_t)jt * 128;
#pragma unroll
      for (int i = 0; i < 8; ++i) {
        const int c = i * 512 + tid;
        const int row = c >> 5, cw = c & 31;
        nt_store4(z, wout + wbase + (size_t)row * S_LEN + cw * 4);
      }
    }
  }

  // ---- merged attention output, bounced through LDS for full-line stores
  __syncthreads();                     // all PV reads of Ws done
  {
    u16* Os = smem;                    // [128][72]
#pragma unroll
    for (int ni = 0; ni < 4; ++ni)
#pragma unroll
      for (int r = 0; r < 4; ++r)
        Os[(wv * 16 + rhi * 4 + r) * 72 + ni * 16 + rlow] = f2bf(opv[ni][r]);
    __syncthreads();
#pragma unroll
    for (int i = 0; i < 2; ++i) {
      const int c = i * 512 + tid;     // 1024 us8 chunks: 128 rows x 8
      const int row = c >> 3, cw = c & 7;
      const us8 t = *(const us8*)&Os[row * 72 + cw * 8];
      *(us8*)(am + headoff + (size_t)(q0 + row) * DMODEL + cw * 8) = t;
    }
  }
}

// ---------------------------------------------------------------------------
extern "C" void kernel_launch(void* const* d_in, const int* in_sizes, int n_in,
                              void* d_out, int out_size, void* d_ws, size_t ws_size,
                              hipStream_t stream) {
  const float* q  = (const float*)d_in[0];
  const float* k  = (const float*)d_in[1];
  const float* v  = (const float*)d_in[2];
  // d_in[3] = causal mask (int32) -- fixed triu(1), applied analytically
  const float* Wq = (const float*)d_in[4];
  const float* bq = (const float*)d_in[5];
  const float* Wk = (const float*)d_in[6];
  const float* bk = (const float*)d_in[7];
  const float* Wv = (const float*)d_in[8];
  const float* bv = (const float*)d_in[9];
  const float* Wo = (const float*)d_in[10];
  const float* bo = (const float*)d_in[11];

  const size_t proj_elems = (size_t)NB * S_LEN * DMODEL;  // 8388608
  const size_t w_elems    = (size_t)DMODEL * DMODEL;      // 1048576
  float* out0 = (float*)d_out;
  float* wts  = out0 + proj_elems;     // fp32 weights region (268.4M floats)

  // persistent bf16 scratch in d_ws (must survive attention kernel)
  u16* qh  = (u16*)d_ws;
  u16* kh  = qh + proj_elems;
  u16* vh  = kh + proj_elems;
  u16* am  = vh + proj_elems;
  u16* wco = am + proj_elems;          // bf16 Wo

  // transient bf16 weight scratch inside the (not-yet-written) weights region
  u16* wq_ = (u16*)wts;
  u16* wk_ = wq_ + w_elems;
  u16* wv_ = wk_ + w_elems;

  const int n8w = (int)(w_elems / 8);      // 131072

  cvt4<<<dim3(n8w / 256, 4), dim3(256), 0, stream>>>(Wq, Wk, Wv, Wo,
                                                     wq_, wk_, wv_, wco, n8w);
  gemm_qkv<<<dim3(64, 8, 3), dim3(256), 0, stream>>>(q, k, v, wq_, wk_, wv_,
                                                     bq, bk, bv, qh, kh, vh);
  attn_fused<<<dim3(1024), dim3(512), 0, stream>>>(qh, kh, vh, wts, am);
  gemm_o<<<dim3(64, 8), dim3(256), 0, stream>>>(am, wco, bo, out0);
}

// Round 8
// 355.653 us; speedup vs baseline: 1.0664x; 1.0397x over previous
//
#include <hip/hip_runtime.h>
#include <stdint.h>

typedef unsigned short u16;
typedef __attribute__((ext_vector_type(8))) short bf16x8;
typedef __attribute__((ext_vector_type(8))) unsigned short us8;
typedef __attribute__((ext_vector_type(4))) float f32x4;

typedef __attribute__((address_space(1))) void as1_void;
typedef __attribute__((address_space(3))) void as3_void;

#define S_LEN 2048
#define DMODEL 1024
#define DH 64
#define NHEADS 16
#define NB 4
#define GM (NB * S_LEN)   // 8192
#define GN DMODEL         // 1024
#define GK DMODEL         // 1024
#define SCALE 0.03125f    // 1/sqrt(1024)

__device__ __forceinline__ void gload16(const void* g, void* l) {
  __builtin_amdgcn_global_load_lds((const as1_void*)g, (as3_void*)l, 16, 0, 0);
}
__device__ __forceinline__ float bf2f(u16 u) {
  union { unsigned int i; float f; } x; x.i = ((unsigned int)u) << 16; return x.f;
}
__device__ __forceinline__ u16 f2bf(float f) {
  union { float f; unsigned int i; } x; x.f = f;
  unsigned int u = x.i + 0x7fffu + ((x.i >> 16) & 1u);
  return (u16)(u >> 16);
}
__device__ __forceinline__ f32x4 mfma16(bf16x8 a, bf16x8 b, f32x4 c) {
  return __builtin_amdgcn_mfma_f32_16x16x32_bf16(a, b, c, 0, 0, 0);
}
__device__ __forceinline__ void nt_store4(f32x4 v, float* p) {
  __builtin_nontemporal_store(v, (f32x4*)p);
}

// ---------------------------------------------------------------------------
// fp32 -> bf16 converts, batched
// ---------------------------------------------------------------------------
__device__ __forceinline__ void cvt_chunk(const float* s, u16* d, int i) {
  const f32x4 a = *(const f32x4*)(s + (size_t)i * 8);
  const f32x4 b = *(const f32x4*)(s + (size_t)i * 8 + 4);
  us8 o;
  o[0] = f2bf(a[0]); o[1] = f2bf(a[1]); o[2] = f2bf(a[2]); o[3] = f2bf(a[3]);
  o[4] = f2bf(b[0]); o[5] = f2bf(b[1]); o[6] = f2bf(b[2]); o[7] = f2bf(b[3]);
  *(us8*)(d + (size_t)i * 8) = o;
}
__global__ __launch_bounds__(256)
void cvt3(const float* __restrict__ s0, const float* __restrict__ s1,
          const float* __restrict__ s2, u16* __restrict__ d0,
          u16* __restrict__ d1, u16* __restrict__ d2, int n8) {
  const int i = blockIdx.x * 256 + threadIdx.x;
  if (i >= n8) return;
  const float* s; u16* d;
  if (blockIdx.y == 0)      { s = s0; d = d0; }
  else if (blockIdx.y == 1) { s = s1; d = d1; }
  else                      { s = s2; d = d2; }
  cvt_chunk(s, d, i);
}
__global__ __launch_bounds__(256)
void cvt4(const float* __restrict__ s0, const float* __restrict__ s1,
          const float* __restrict__ s2, const float* __restrict__ s3,
          u16* __restrict__ d0, u16* __restrict__ d1,
          u16* __restrict__ d2, u16* __restrict__ d3, int n8) {
  const int i = blockIdx.x * 256 + threadIdx.x;
  if (i >= n8) return;
  const float* s; u16* d;
  if (blockIdx.y == 0)      { s = s0; d = d0; }
  else if (blockIdx.y == 1) { s = s1; d = d1; }
  else if (blockIdx.y == 2) { s = s2; d = d2; }
  else                      { s = s3; d = d3; }
  cvt_chunk(s, d, i);
}

// ---------------------------------------------------------------------------
// GEMM body: C[8192,1024] = A[8192,1024] @ W[1024,1024]^T + bias
// 128x128 tile, BK=64, 4 waves (2x2), 64x64/wave, 2-phase LDS double-buffer.
// Epilogue bounces C tile through LDS for full-line global stores.
// ---------------------------------------------------------------------------
template<bool OUTF>
__device__ __forceinline__ void gemm_body(const u16* __restrict__ A,
                                          const u16* __restrict__ W,
                                          const float* __restrict__ bias,
                                          void* __restrict__ Cv,
                                          u16* smem) {
  u16* As = smem;
  u16* Bs = smem + 2 * 8192;
  const int tid  = threadIdx.x;
  const int lane = tid & 63;
  const int wv   = tid >> 6;
  const int wr   = wv >> 1, wc = wv & 1;
  const int rlow = lane & 15, rhi = lane >> 4;
  const int m0 = blockIdx.x * 128;
  const int n0 = blockIdx.y * 128;

  f32x4 acc[4][4];
#pragma unroll
  for (int i = 0; i < 4; ++i)
#pragma unroll
    for (int j = 0; j < 4; ++j) acc[i][j] = (f32x4){0.f, 0.f, 0.f, 0.f};

#define STAGE_G(bufi, kk)                                                     \
  {                                                                           \
    _Pragma("unroll")                                                         \
    for (int i = 0; i < 4; ++i) {                                             \
      const int c = i * 256 + tid;                                            \
      const int row = c >> 3, cw = c & 7;                                     \
      const int koff = ((kk) << 6) + ((cw ^ (row & 7)) << 3);                 \
      gload16(A + (size_t)(m0 + row) * GK + koff,                             \
              &As[(bufi) * 8192 + ((c - lane) << 3)]);                        \
      gload16(W + (size_t)(n0 + row) * GK + koff,                             \
              &Bs[(bufi) * 8192 + ((c - lane) << 3)]);                        \
    }                                                                         \
  }

  const int nk = GK >> 6;  // 16
  STAGE_G(0, 0);
  __syncthreads();
  int buf = 0;
  for (int kk = 0; kk < nk; ++kk) {
    if (kk + 1 < nk) STAGE_G(buf ^ 1, kk + 1);
    const u16* Ab = &As[buf * 8192];
    const u16* Bb = &Bs[buf * 8192];
    bf16x8 af[4][2], bfr[4][2];
#pragma unroll
    for (int mi = 0; mi < 4; ++mi) {
      const int row = wr * 64 + mi * 16 + rlow;
#pragma unroll
      for (int k2 = 0; k2 < 2; ++k2)
        af[mi][k2] = *(const bf16x8*)&Ab[row * 64 + (((rhi + k2 * 4) ^ (row & 7)) << 3)];
    }
#pragma unroll
    for (int ni = 0; ni < 4; ++ni) {
      const int row = wc * 64 + ni * 16 + rlow;
#pragma unroll
      for (int k2 = 0; k2 < 2; ++k2)
        bfr[ni][k2] = *(const bf16x8*)&Bb[row * 64 + (((rhi + k2 * 4) ^ (row & 7)) << 3)];
    }
#pragma unroll
    for (int mi = 0; mi < 4; ++mi)
#pragma unroll
      for (int ni = 0; ni < 4; ++ni) {
        acc[mi][ni] = mfma16(af[mi][0], bfr[ni][0], acc[mi][ni]);
        acc[mi][ni] = mfma16(af[mi][1], bfr[ni][1], acc[mi][ni]);
      }
    __syncthreads();  // drains vmcnt: next tile resident; buf safe to reuse
    buf ^= 1;
  }
#undef STAGE_G

  // ---- epilogue: bounce C tile through LDS for full-line stores
  if constexpr (OUTF) {
    float* Cs = (float*)smem;               // [128][128] fp32 = 64 KB
#pragma unroll
    for (int ni = 0; ni < 4; ++ni) {
      const int col = wc * 64 + ni * 16 + rlow;
      const float bv = bias[n0 + col];
#pragma unroll
      for (int mi = 0; mi < 4; ++mi)
#pragma unroll
        for (int r = 0; r < 4; ++r)
          Cs[(wr * 64 + mi * 16 + rhi * 4 + r) * 128 + col] = acc[mi][ni][r] + bv;
    }
    __syncthreads();
#pragma unroll
    for (int i = 0; i < 16; ++i) {
      const int c = i * 256 + tid;          // 4096 f32x4 chunks
      const int row = c >> 5, cw = c & 31;
      const f32x4 t = *(const f32x4*)&Cs[row * 128 + cw * 4];
      nt_store4(t, &((float*)Cv)[(size_t)(m0 + row) * GN + n0 + cw * 4]);
    }
  } else {
    u16* Cs = smem;                          // [128][144] bf16 (padded)
#pragma unroll
    for (int ni = 0; ni < 4; ++ni) {
      const int col = wc * 64 + ni * 16 + rlow;
      const float bv = bias[n0 + col];
#pragma unroll
      for (int mi = 0; mi < 4; ++mi)
#pragma unroll
        for (int r = 0; r < 4; ++r)
          Cs[(wr * 64 + mi * 16 + rhi * 4 + r) * 144 + col] = f2bf(acc[mi][ni][r] + bv);
    }
    __syncthreads();
#pragma unroll
    for (int i = 0; i < 8; ++i) {
      const int c = i * 256 + tid;          // 2048 us8 chunks
      const int row = c >> 4, cw = c & 15;
      const us8 t = *(const us8*)&Cs[row * 144 + cw * 8];
      *(us8*)&((u16*)Cv)[(size_t)(m0 + row) * GN + n0 + cw * 8] = t;
    }
  }
}

__global__ __launch_bounds__(256, 2)
void gemm_qkv(const u16* __restrict__ xq, const u16* __restrict__ xk,
              const u16* __restrict__ xv, const u16* __restrict__ wq,
              const u16* __restrict__ wk, const u16* __restrict__ wv,
              const float* __restrict__ bq, const float* __restrict__ bk,
              const float* __restrict__ bv, u16* __restrict__ oq,
              u16* __restrict__ ok, u16* __restrict__ ov) {
  __shared__ u16 smem[4 * 8192];
  const u16 *A, *W; const float* bias; u16* C;
  if (blockIdx.z == 0)      { A = xq; W = wq; bias = bq; C = oq; }
  else if (blockIdx.z == 1) { A = xk; W = wk; bias = bk; C = ok; }
  else                      { A = xv; W = wv; bias = bv; C = ov; }
  gemm_body<false>(A, W, bias, C, smem);
}

__global__ __launch_bounds__(256, 2)
void gemm_o(const u16* __restrict__ A, const u16* __restrict__ W,
            const float* __restrict__ bias, float* __restrict__ C) {
  __shared__ u16 smem[4 * 8192];
  gemm_body<true>(A, W, bias, C, smem);
}

// ---------------------------------------------------------------------------
// Fused causal attention for one (b,h, 128-row Q tile).
// Pass 1: QK^T -> per-row sum of exp; K double-buffered (Ws region is dead in
// pass 1 -> alternate K buffer; 1 barrier/tile, loads in flight over compute).
// Pass 2: recompute QK^T, bf16 weights into Ws, barrier, full-line NT f32x4
// store of the weight tile, PV MFMA from Ws & VT. VT staged conflict-free
// (wave->fixed d0, lane->j: distinct banks across all 64 lanes).
// LDS: Qs/Ws/Kb1 union -> 67 KB -> 2 blocks/CU at (512,4).
// ---------------------------------------------------------------------------
__global__ __launch_bounds__(512, 4)
void attn_fused(const u16* __restrict__ qh, const u16* __restrict__ kh,
                const u16* __restrict__ vh, float* __restrict__ wout,
                u16* __restrict__ am)
{
  __shared__ u16 smem[34304];          // 67 KB
  u16* Ws  = smem;                     // [128][136] (pass 2)
  u16* Qs  = smem;                     // [128][64]  (prologue only, union)
  u16* Kb1 = smem;                     // [128][64]  (pass-1 alt K buf, union)
  u16* Kb0 = smem + 17408;             // [128][64]
  u16* VT  = smem + 17408 + 8192;      // [64][136]

  const int tid = threadIdx.x, lane = tid & 63, wv = tid >> 6;
  const int rlow = lane & 15, rhi = lane >> 4;
  const int idx = blockIdx.x;
  const int bh  = idx & 63;            // consecutive blocks spread across heads
  const int qt  = 15 - (idx >> 6);     // heaviest Q-tiles scheduled first
  const int b = bh >> 4, h = bh & 15;
  const int q0 = qt << 7;
  const size_t headoff = (size_t)b * S_LEN * DMODEL + h * DH;

#define STAGE_K(dst, jtile)                                                   \
  {                                                                           \
    _Pragma("unroll")                                                         \
    for (int i = 0; i < 2; ++i) {                                             \
      const int c = i * 512 + tid;                                            \
      const int row = c >> 3, cw = c & 7;                                     \
      gload16(kh + headoff + (size_t)((jtile) * 128 + row) * DMODEL +         \
              ((cw ^ (row & 7)) << 3), &(dst)[(c - lane) << 3]);              \
    }                                                                         \
  }

  // ---- stage Q tile (swizzled source -> linear LDS)
#pragma unroll
  for (int i = 0; i < 2; ++i) {
    const int c = i * 512 + tid;
    const int row = c >> 3, cw = c & 7;
    gload16(qh + headoff + (size_t)(q0 + row) * DMODEL + ((cw ^ (row & 7)) << 3),
            &Qs[(c - lane) << 3]);
  }
  __syncthreads();
  bf16x8 qf[2];
  {
    const int row = wv * 16 + rlow;
#pragma unroll
    for (int k2 = 0; k2 < 2; ++k2)
      qf[k2] = *(const bf16x8*)&Qs[row * 64 + (((rhi + k2 * 4) ^ (row & 7)) << 3)];
  }

  const int gi_base = q0 + wv * 16 + rhi * 4;
  float ssum[4] = {0.f, 0.f, 0.f, 0.f};

  // ---------------- pass 1: row sums of exp (K double-buffered) ----------
  STAGE_K(Kb0, 0);
  for (int jt = 0; jt <= qt; ++jt) {
    __syncthreads();   // stage(jt) resident; compute(jt-1) readers done
    const u16* kcur = (jt & 1) ? Kb1 : Kb0;
    if (jt < qt) {
      u16* knxt = (jt & 1) ? Kb0 : Kb1;
      STAGE_K(knxt, jt + 1);
    }
    const bool diag = (jt == qt);
    float pexp[4] = {0.f, 0.f, 0.f, 0.f};
#pragma unroll
    for (int half = 0; half < 2; ++half) {
      f32x4 acc[4];
#pragma unroll
      for (int ni = 0; ni < 4; ++ni) acc[ni] = (f32x4){0.f, 0.f, 0.f, 0.f};
#pragma unroll
      for (int k2 = 0; k2 < 2; ++k2) {
#pragma unroll
        for (int ni = 0; ni < 4; ++ni) {
          const int row = (half * 4 + ni) * 16 + rlow;
          bf16x8 kf = *(const bf16x8*)&kcur[row * 64 + (((rhi + k2 * 4) ^ (row & 7)) << 3)];
          acc[ni] = mfma16(qf[k2], kf, acc[ni]);
        }
      }
#pragma unroll
      for (int ni = 0; ni < 4; ++ni) {
        const int gj = jt * 128 + (half * 4 + ni) * 16 + rlow;
#pragma unroll
        for (int r = 0; r < 4; ++r) {
          if (!diag || gj <= gi_base + r) pexp[r] += __expf(acc[ni][r] * SCALE);
        }
      }
    }
#pragma unroll
    for (int r = 0; r < 4; ++r) {
      float p = pexp[r];
      p += __shfl_xor(p, 1);
      p += __shfl_xor(p, 2);
      p += __shfl_xor(p, 4);
      p += __shfl_xor(p, 8);
      ssum[r] += p;
    }
  }
  float inv_s[4];
#pragma unroll
  for (int r = 0; r < 4; ++r) inv_s[r] = 1.f / ssum[r];

  f32x4 opv[4];
#pragma unroll
  for (int ni = 0; ni < 4; ++ni) opv[ni] = (f32x4){0.f, 0.f, 0.f, 0.f};

  // ---------------- pass 2: weights + PV ----------------
  for (int jt = 0; jt <= qt; ++jt) {
    __syncthreads();   // prev iter's PV (VT/Ws readers) complete
    STAGE_K(Kb0, jt);
    // stage V transposed: VT[d][j]; wave->fixed d0, lane->j (conflict-free)
#pragma unroll
    for (int i = 0; i < 2; ++i) {
      const int j = (i << 6) | lane;
      const int d0v = wv << 3;
      bf16x8 vv = *(const bf16x8*)(vh + headoff + (size_t)(jt * 128 + j) * DMODEL + d0v);
#pragma unroll
      for (int e = 0; e < 8; ++e) VT[(d0v + e) * 136 + j] = (u16)vv[e];
    }
    __syncthreads();
    const bool diag = (jt == qt);
#pragma unroll
    for (int half = 0; half < 2; ++half) {
      f32x4 acc[4];
#pragma unroll
      for (int ni = 0; ni < 4; ++ni) acc[ni] = (f32x4){0.f, 0.f, 0.f, 0.f};
#pragma unroll
      for (int k2 = 0; k2 < 2; ++k2) {
#pragma unroll
        for (int ni = 0; ni < 4; ++ni) {
          const int row = (half * 4 + ni) * 16 + rlow;
          bf16x8 kf = *(const bf16x8*)&Kb0[row * 64 + (((rhi + k2 * 4) ^ (row & 7)) << 3)];
          acc[ni] = mfma16(qf[k2], kf, acc[ni]);
        }
      }
#pragma unroll
      for (int ni = 0; ni < 4; ++ni) {
        const int col = (half * 4 + ni) * 16 + rlow;
        const int gj = jt * 128 + col;
#pragma unroll
        for (int r = 0; r < 4; ++r) {
          float w = 0.f;
          if (!diag || gj <= gi_base + r) w = __expf(acc[ni][r] * SCALE) * inv_s[r];
          Ws[(wv * 16 + rhi * 4 + r) * 136 + col] = f2bf(w);
        }
      }
    }
    __syncthreads();   // Ws tile complete
    // full-line NONTEMPORAL fp32 store of the weights tile
    {
      const size_t wbase = ((size_t)bh * S_LEN + q0) * S_LEN + (size_t)jt * 128;
#pragma unroll
      for (int i = 0; i < 8; ++i) {
        const int c = i * 512 + tid;        // 4096 f32x4 chunks: 128 rows x 32
        const int row = c >> 5, cw = c & 31;
        f32x4 t;
        t[0] = bf2f(Ws[row * 136 + cw * 4 + 0]);
        t[1] = bf2f(Ws[row * 136 + cw * 4 + 1]);
        t[2] = bf2f(Ws[row * 136 + cw * 4 + 2]);
        t[3] = bf2f(Ws[row * 136 + cw * 4 + 3]);
        nt_store4(t, wout + wbase + (size_t)row * S_LEN + cw * 4);
      }
    }
    // PV: A from Ws (this wave's 16 rows), B from VT
#pragma unroll
    for (int k4 = 0; k4 < 4; ++k4) {
      const bf16x8 afr = *(const bf16x8*)&Ws[(wv * 16 + rlow) * 136 + rhi * 8 + k4 * 32];
#pragma unroll
      for (int ni = 0; ni < 4; ++ni) {
        const bf16x8 vfr = *(const bf16x8*)&VT[(ni * 16 + rlow) * 136 + rhi * 8 + k4 * 32];
        opv[ni] = mfma16(afr, vfr, opv[ni]);
      }
    }
  }
#undef STAGE_K

  // ---- zero tiles above the diagonal (every d_out byte written exactly once)
  {
    const f32x4 z = {0.f, 0.f, 0.f, 0.f};
    for (int jt = qt + 1; jt < 16; ++jt) {
      const size_t wbase = ((size_t)bh * S_LEN + q0) * S_LEN + (size_t)jt * 128;
#pragma unroll
      for (int i = 0; i < 8; ++i) {
        const int c = i * 512 + tid;
        const int row = c >> 5, cw = c & 31;
        nt_store4(z, wout + wbase + (size_t)row * S_LEN + cw * 4);
      }
    }
  }

  // ---- merged attention output, bounced through LDS for full-line stores
  __syncthreads();                     // all PV reads of Ws done
  {
    u16* Os = smem;                    // [128][72]
#pragma unroll
    for (int ni = 0; ni < 4; ++ni)
#pragma unroll
      for (int r = 0; r < 4; ++r)
        Os[(wv * 16 + rhi * 4 + r) * 72 + ni * 16 + rlow] = f2bf(opv[ni][r]);
    __syncthreads();
#pragma unroll
    for (int i = 0; i < 2; ++i) {
      const int c = i * 512 + tid;     // 1024 us8 chunks: 128 rows x 8
      const int row = c >> 3, cw = c & 7;
      const us8 t = *(const us8*)&Os[row * 72 + cw * 8];
      *(us8*)(am + headoff + (size_t)(q0 + row) * DMODEL + cw * 8) = t;
    }
  }
}

// ---------------------------------------------------------------------------
extern "C" void kernel_launch(void* const* d_in, const int* in_sizes, int n_in,
                              void* d_out, int out_size, void* d_ws, size_t ws_size,
                              hipStream_t stream) {
  const float* q  = (const float*)d_in[0];
  const float* k  = (const float*)d_in[1];
  const float* v  = (const float*)d_in[2];
  // d_in[3] = causal mask (int32) -- fixed triu(1), applied analytically
  const float* Wq = (const float*)d_in[4];
  const float* bq = (const float*)d_in[5];
  const float* Wk = (const float*)d_in[6];
  const float* bk = (const float*)d_in[7];
  const float* Wv = (const float*)d_in[8];
  const float* bv = (const float*)d_in[9];
  const float* Wo = (const float*)d_in[10];
  const float* bo = (const float*)d_in[11];

  const size_t proj_elems = (size_t)NB * S_LEN * DMODEL;  // 8388608
  const size_t w_elems    = (size_t)DMODEL * DMODEL;      // 1048576
  float* out0 = (float*)d_out;
  float* wts  = out0 + proj_elems;     // fp32 weights region (268.4M floats)

  // persistent bf16 scratch in d_ws (must survive attention kernel)
  u16* qh  = (u16*)d_ws;
  u16* kh  = qh + proj_elems;
  u16* vh  = kh + proj_elems;
  u16* am  = vh + proj_elems;
  u16* wco = am + proj_elems;          // bf16 Wo

  // transient bf16 scratch inside the (not-yet-written) weights region
  u16* xq = (u16*)wts;
  u16* xk = xq + proj_elems;
  u16* xv = xk + proj_elems;
  u16* wq_ = xv + proj_elems;
  u16* wk_ = wq_ + w_elems;
  u16* wv_ = wk_ + w_elems;

  const int n8x = (int)(proj_elems / 8);   // 1048576
  const int n8w = (int)(w_elems / 8);      // 131072

  cvt3<<<dim3(n8x / 256, 3), dim3(256), 0, stream>>>(q, k, v, xq, xk, xv, n8x);
  cvt4<<<dim3(n8w / 256, 4), dim3(256), 0, stream>>>(Wq, Wk, Wv, Wo,
                                                     wq_, wk_, wv_, wco, n8w);
  gemm_qkv<<<dim3(64, 8, 3), dim3(256), 0, stream>>>(xq, xk, xv, wq_, wk_, wv_,
                                                     bq, bk, bv, qh, kh, vh);
  attn_fused<<<dim3(1024), dim3(512), 0, stream>>>(qh, kh, vh, wts, am);
  gemm_o<<<dim3(64, 8), dim3(256), 0, stream>>>(am, wco, bo, out0);
}